// Round 1
// baseline (502.600 us; speedup 1.0000x reference)
//
#include <hip/hip_runtime.h>

typedef __bf16 bf16_t;
typedef __bf16 bf16x8 __attribute__((ext_vector_type(8)));
typedef float f32x4 __attribute__((ext_vector_type(4)));

#define MFMA16(a, b, c) __builtin_amdgcn_mfma_f32_16x16x32_bf16((a), (b), (c), 0, 0, 0)

constexpr int B_ = 4, S_ = 2048, D_ = 1024, H_ = 16, DH_ = 64;

// ---------- prep: W[H][D][64] -> Wt[H*64][D] bf16 (B^T layout) ----------
__global__ __launch_bounds__(256) void prep_w(const float* __restrict__ W,
                                              bf16_t* __restrict__ Wt) {
  __shared__ float tile[64][65];
  int h = blockIdx.y, k0 = blockIdx.x * 64, tid = threadIdx.x;
  int r = tid >> 2, cb = (tid & 3) * 16;
  const float* src = W + h * (D_ * DH_) + (k0 + r) * DH_ + cb;
  float4 f0 = ((const float4*)src)[0];
  float4 f1 = ((const float4*)src)[1];
  float4 f2 = ((const float4*)src)[2];
  float4 f3 = ((const float4*)src)[3];
  tile[r][cb + 0] = f0.x;  tile[r][cb + 1] = f0.y;  tile[r][cb + 2] = f0.z;  tile[r][cb + 3] = f0.w;
  tile[r][cb + 4] = f1.x;  tile[r][cb + 5] = f1.y;  tile[r][cb + 6] = f1.z;  tile[r][cb + 7] = f1.w;
  tile[r][cb + 8] = f2.x;  tile[r][cb + 9] = f2.y;  tile[r][cb + 10] = f2.z; tile[r][cb + 11] = f2.w;
  tile[r][cb + 12] = f3.x; tile[r][cb + 13] = f3.y; tile[r][cb + 14] = f3.z; tile[r][cb + 15] = f3.w;
  __syncthreads();
  int j = tid >> 2, kb = (tid & 3) * 16;
  bf16_t tmp[16] __attribute__((aligned(16)));
#pragma unroll
  for (int c = 0; c < 16; ++c) tmp[c] = (bf16_t)tile[kb + c][j];
  bf16_t* dst = Wt + (h * 64 + j) * D_ + k0 + kb;
  *(uint4*)dst = ((uint4*)tmp)[0];
  *(uint4*)(dst + 8) = ((uint4*)tmp)[1];
}

__global__ __launch_bounds__(256) void prep_wo(const float* __restrict__ W,
                                               bf16_t* __restrict__ Wt) {
  int i = (blockIdx.x * 256 + threadIdx.x) * 4;
  float4 f = *(const float4*)&W[i];
  bf16_t t[4] __attribute__((aligned(8)));
  t[0] = (bf16_t)f.x; t[1] = (bf16_t)f.y; t[2] = (bf16_t)f.z; t[3] = (bf16_t)f.w;
  *(uint2*)&Wt[i] = *(uint2*)t;
}

// ---------- QKV projection GEMM: [8192,1024] x Wt^T -> bf16 ----------
__global__ __launch_bounds__(256) void gemm_qkv(
    const float* __restrict__ Aq, const float* __restrict__ Ak, const float* __restrict__ Av,
    const bf16_t* __restrict__ Wt_all,
    bf16_t* __restrict__ Qp, bf16_t* __restrict__ Kp, bf16_t* __restrict__ Vt) {
  __shared__ __attribute__((aligned(16))) bf16_t Al[128][40];
  __shared__ __attribute__((aligned(16))) bf16_t Bl[128][40];
  int gz = blockIdx.z;
  const float* A = gz == 0 ? Aq : (gz == 1 ? Ak : Av);
  const bf16_t* W = Wt_all + gz * (D_ * D_);
  int m0 = blockIdx.x * 128, n0 = blockIdx.y * 128;
  int tid = threadIdx.x, lane = tid & 63, w = tid >> 6;
  int wm = (w & 1) * 64, wn = (w >> 1) * 64;
  int l15 = lane & 15, quad = lane >> 4;
  int srow = tid >> 1, skc = (tid & 1) * 16;

  f32x4 acc[4][4] = {};

  for (int kk = 0; kk < D_; kk += 32) {
    const float* ap = A + (m0 + srow) * D_ + kk + skc;
    float4 f0 = ((const float4*)ap)[0];
    float4 f1 = ((const float4*)ap)[1];
    float4 f2 = ((const float4*)ap)[2];
    float4 f3 = ((const float4*)ap)[3];
    bf16_t t[16] __attribute__((aligned(16)));
    t[0] = (bf16_t)f0.x;  t[1] = (bf16_t)f0.y;  t[2] = (bf16_t)f0.z;  t[3] = (bf16_t)f0.w;
    t[4] = (bf16_t)f1.x;  t[5] = (bf16_t)f1.y;  t[6] = (bf16_t)f1.z;  t[7] = (bf16_t)f1.w;
    t[8] = (bf16_t)f2.x;  t[9] = (bf16_t)f2.y;  t[10] = (bf16_t)f2.z; t[11] = (bf16_t)f2.w;
    t[12] = (bf16_t)f3.x; t[13] = (bf16_t)f3.y; t[14] = (bf16_t)f3.z; t[15] = (bf16_t)f3.w;
    *(uint4*)&Al[srow][skc] = ((uint4*)t)[0];
    *(uint4*)&Al[srow][skc + 8] = ((uint4*)t)[1];
    const uint4* bp = (const uint4*)(W + (n0 + srow) * D_ + kk + skc);
    *(uint4*)&Bl[srow][skc] = bp[0];
    *(uint4*)&Bl[srow][skc + 8] = bp[1];
    __syncthreads();
    bf16x8 af[4], bfr[4];
#pragma unroll
    for (int i = 0; i < 4; ++i) {
      af[i] = *(const bf16x8*)&Al[wm + i * 16 + l15][quad * 8];
      bfr[i] = *(const bf16x8*)&Bl[wn + i * 16 + l15][quad * 8];
    }
#pragma unroll
    for (int i = 0; i < 4; ++i)
#pragma unroll
      for (int j = 0; j < 4; ++j) acc[i][j] = MFMA16(af[i], bfr[j], acc[i][j]);
    __syncthreads();
  }

  if (gz < 2) {
    bf16_t* Out = gz == 0 ? Qp : Kp;
#pragma unroll
    for (int i = 0; i < 4; ++i)
#pragma unroll
      for (int j = 0; j < 4; ++j)
#pragma unroll
        for (int r = 0; r < 4; ++r) {
          int m = m0 + wm + i * 16 + quad * 4 + r;
          int n = n0 + wn + j * 16 + l15;
          Out[m * D_ + n] = (bf16_t)acc[i][j][r];
        }
  } else {
#pragma unroll
    for (int i = 0; i < 4; ++i)
#pragma unroll
      for (int j = 0; j < 4; ++j) {
        int m = m0 + wm + i * 16 + quad * 4;
        int b = m >> 11, sl = m & (S_ - 1);
        int n = n0 + wn + j * 16 + l15;
        int h = n >> 6, d = n & 63;
        bf16_t t4[4] __attribute__((aligned(8)));
        t4[0] = (bf16_t)acc[i][j][0]; t4[1] = (bf16_t)acc[i][j][1];
        t4[2] = (bf16_t)acc[i][j][2]; t4[3] = (bf16_t)acc[i][j][3];
        *(uint2*)&Vt[((b * H_ + h) * DH_ + d) * S_ + sl] = *(uint2*)t4;
      }
  }
}

// ---------- flash attention, causal ----------
__global__ __launch_bounds__(256) void attn(
    const bf16_t* __restrict__ Qp, const bf16_t* __restrict__ Kp,
    const bf16_t* __restrict__ Vt, bf16_t* __restrict__ Ob) {
  __shared__ __attribute__((aligned(16))) bf16_t Kl[64][72];
  __shared__ __attribute__((aligned(16))) bf16_t Vl[64][72];
  __shared__ __attribute__((aligned(16))) bf16_t Pl[4][16][72];
  int qt = (int)(gridDim.x - 1) - (int)blockIdx.x;  // heavy blocks first
  int bh = blockIdx.y, b = bh >> 4, h = bh & 15;
  int tid = threadIdx.x, lane = tid & 63, w = tid >> 6;
  int l15 = lane & 15, quad = lane >> 4;
  const float csc = 0.125f * 1.44269504f;  // 1/sqrt(64) * log2(e)

  int sq_base = qt * 64 + w * 16;
  const bf16_t* qptr = Qp + (b * S_ + sq_base + l15) * D_ + h * DH_ + quad * 8;
  bf16x8 qa0 = *(const bf16x8*)qptr;
  bf16x8 qa1 = *(const bf16x8*)(qptr + 32);

  f32x4 o[4] = {};
  float mrow[4], lrow[4];
#pragma unroll
  for (int r = 0; r < 4; ++r) { mrow[r] = -3.0e38f; lrow[r] = 0.f; }

  int srow = tid >> 2, scb = (tid & 3) * 16;

  for (int jt = 0; jt <= qt; ++jt) {
    const uint4* kp = (const uint4*)(Kp + (b * S_ + jt * 64 + srow) * D_ + h * DH_ + scb);
    *(uint4*)&Kl[srow][scb] = kp[0];
    *(uint4*)&Kl[srow][scb + 8] = kp[1];
    const uint4* vp = (const uint4*)(Vt + (bh * DH_ + srow) * S_ + jt * 64 + scb);
    *(uint4*)&Vl[srow][scb] = vp[0];
    *(uint4*)&Vl[srow][scb + 8] = vp[1];
    __syncthreads();

    f32x4 sc[4];
#pragma unroll
    for (int n = 0; n < 4; ++n) {
      bf16x8 kb0 = *(const bf16x8*)&Kl[n * 16 + l15][quad * 8];
      bf16x8 kb1 = *(const bf16x8*)&Kl[n * 16 + l15][32 + quad * 8];
      f32x4 z = {};
      z = MFMA16(qa0, kb0, z);
      z = MFMA16(qa1, kb1, z);
      sc[n] = z;
    }

    if (jt == qt) {
#pragma unroll
      for (int n = 0; n < 4; ++n)
#pragma unroll
        for (int r = 0; r < 4; ++r) {
          int col = n * 16 + l15, row = w * 16 + quad * 4 + r;
          if (col > row) sc[n][r] = -3.0e38f;
        }
    }

    float mnew[4], alpha[4];
#pragma unroll
    for (int r = 0; r < 4; ++r) {
      float mx = fmaxf(fmaxf(sc[0][r], sc[1][r]), fmaxf(sc[2][r], sc[3][r]));
      mx = fmaxf(mx, __shfl_xor(mx, 1));
      mx = fmaxf(mx, __shfl_xor(mx, 2));
      mx = fmaxf(mx, __shfl_xor(mx, 4));
      mx = fmaxf(mx, __shfl_xor(mx, 8));
      mnew[r] = fmaxf(mrow[r], mx);
      alpha[r] = __builtin_amdgcn_exp2f((mrow[r] - mnew[r]) * csc);
      mrow[r] = mnew[r];
    }
    float rs[4] = {0.f, 0.f, 0.f, 0.f};
#pragma unroll
    for (int n = 0; n < 4; ++n)
#pragma unroll
      for (int r = 0; r < 4; ++r) {
        float p = __builtin_amdgcn_exp2f(sc[n][r] * csc - mnew[r] * csc);
        rs[r] += p;
        Pl[w][quad * 4 + r][n * 16 + l15] = (bf16_t)p;
      }
#pragma unroll
    for (int r = 0; r < 4; ++r) {
      float s = rs[r];
      s += __shfl_xor(s, 1); s += __shfl_xor(s, 2);
      s += __shfl_xor(s, 4); s += __shfl_xor(s, 8);
      lrow[r] = lrow[r] * alpha[r] + s;
    }
#pragma unroll
    for (int n = 0; n < 4; ++n)
#pragma unroll
      for (int r = 0; r < 4; ++r) o[n][r] *= alpha[r];

    asm volatile("s_waitcnt lgkmcnt(0)" ::: "memory");  // P LDS write->read, wave-private

    bf16x8 pa0 = *(const bf16x8*)&Pl[w][l15][quad * 8];
    bf16x8 pa1 = *(const bf16x8*)&Pl[w][l15][32 + quad * 8];
#pragma unroll
    for (int n = 0; n < 4; ++n) {
      bf16x8 vb0 = *(const bf16x8*)&Vl[n * 16 + l15][quad * 8];
      bf16x8 vb1 = *(const bf16x8*)&Vl[n * 16 + l15][32 + quad * 8];
      o[n] = MFMA16(pa0, vb0, o[n]);
      o[n] = MFMA16(pa1, vb1, o[n]);
    }
    __syncthreads();
  }

#pragma unroll
  for (int r = 0; r < 4; ++r) {
    float inv = 1.0f / lrow[r];
    int sq = qt * 64 + w * 16 + quad * 4 + r;
    bf16_t* op = Ob + (b * S_ + sq) * D_ + h * DH_;
#pragma unroll
    for (int n = 0; n < 4; ++n) op[n * 16 + l15] = (bf16_t)(o[n][r] * inv);
  }
}

// ---------- output projection: Ab[8192,1024]bf16 @ Wo^T + bo -> fp32 ----------
__global__ __launch_bounds__(256) void gemm_out(
    const bf16_t* __restrict__ Ab, const bf16_t* __restrict__ Wot,
    const float* __restrict__ bo, float* __restrict__ Out) {
  __shared__ __attribute__((aligned(16))) bf16_t Al[128][40];
  __shared__ __attribute__((aligned(16))) bf16_t Bl[128][40];
  int m0 = blockIdx.x * 128, n0 = blockIdx.y * 128;
  int tid = threadIdx.x, lane = tid & 63, w = tid >> 6;
  int wm = (w & 1) * 64, wn = (w >> 1) * 64;
  int l15 = lane & 15, quad = lane >> 4;
  int srow = tid >> 1, skc = (tid & 1) * 16;

  f32x4 acc[4][4] = {};

  for (int kk = 0; kk < D_; kk += 32) {
    const uint4* ap = (const uint4*)(Ab + (m0 + srow) * D_ + kk + skc);
    *(uint4*)&Al[srow][skc] = ap[0];
    *(uint4*)&Al[srow][skc + 8] = ap[1];
    const uint4* bp = (const uint4*)(Wot + (n0 + srow) * D_ + kk + skc);
    *(uint4*)&Bl[srow][skc] = bp[0];
    *(uint4*)&Bl[srow][skc + 8] = bp[1];
    __syncthreads();
    bf16x8 af[4], bfr[4];
#pragma unroll
    for (int i = 0; i < 4; ++i) {
      af[i] = *(const bf16x8*)&Al[wm + i * 16 + l15][quad * 8];
      bfr[i] = *(const bf16x8*)&Bl[wn + i * 16 + l15][quad * 8];
    }
#pragma unroll
    for (int i = 0; i < 4; ++i)
#pragma unroll
      for (int j = 0; j < 4; ++j) acc[i][j] = MFMA16(af[i], bfr[j], acc[i][j]);
    __syncthreads();
  }

#pragma unroll
  for (int j = 0; j < 4; ++j) {
    int n = n0 + wn + j * 16 + l15;
    float bias = bo[n];
#pragma unroll
    for (int i = 0; i < 4; ++i)
#pragma unroll
      for (int r = 0; r < 4; ++r) {
        int m = m0 + wm + i * 16 + quad * 4 + r;
        Out[m * D_ + n] = acc[i][j][r] + bias;
      }
  }
}

extern "C" void kernel_launch(void* const* d_in, const int* in_sizes, int n_in,
                              void* d_out, int out_size, void* d_ws, size_t ws_size,
                              hipStream_t stream) {
  const float* q = (const float*)d_in[0];
  const float* k = (const float*)d_in[1];
  const float* v = (const float*)d_in[2];
  const float* Wq = (const float*)d_in[3];
  const float* Wk = (const float*)d_in[4];
  const float* Wv = (const float*)d_in[5];
  const float* Wo = (const float*)d_in[6];
  const float* bo = (const float*)d_in[7];
  float* out = (float*)d_out;

  bf16_t* wsb = (bf16_t*)d_ws;
  const size_t MD = (size_t)8192 * 1024;   // 8.4M elements
  bf16_t* Wqt = wsb;                        // 3 x 1M (Wq,Wk,Wv transposed)
  bf16_t* Wot = wsb + 3 * (size_t)(D_ * D_);
  bf16_t* Qp  = wsb + 4 * (size_t)(D_ * D_);
  bf16_t* Kp  = Qp + MD;
  bf16_t* Vt  = Kp + MD;
  bf16_t* Ab  = Vt + MD;

  prep_w<<<dim3(16, 16), 256, 0, stream>>>(Wq, Wqt);
  prep_w<<<dim3(16, 16), 256, 0, stream>>>(Wk, Wqt + (size_t)(D_ * D_));
  prep_w<<<dim3(16, 16), 256, 0, stream>>>(Wv, Wqt + 2 * (size_t)(D_ * D_));
  prep_wo<<<1024, 256, 0, stream>>>(Wo, Wot);
  gemm_qkv<<<dim3(64, 8, 3), 256, 0, stream>>>(q, k, v, Wqt, Qp, Kp, Vt);
  attn<<<dim3(32, 64), 256, 0, stream>>>(Qp, Kp, Vt, Ab);
  gemm_out<<<dim3(64, 8), 256, 0, stream>>>(Ab, Wot, bo, out);
}

// Round 2
// 374.024 us; speedup vs baseline: 1.3438x; 1.3438x over previous
//
#include <hip/hip_runtime.h>

typedef __bf16 bf16_t;
typedef __bf16 bf16x8 __attribute__((ext_vector_type(8)));
typedef float f32x4 __attribute__((ext_vector_type(4)));

#define MFMA16(a, b, c) __builtin_amdgcn_mfma_f32_16x16x32_bf16((a), (b), (c), 0, 0, 0)

// async global->LDS, 16B per lane; LDS dest = wave-uniform base + lane*16
#define GLOAD_LDS16(gsrc, ldst)                                                      \
  __builtin_amdgcn_global_load_lds(                                                  \
      (const __attribute__((address_space(1))) uint32_t*)(const void*)(gsrc),        \
      (__attribute__((address_space(3))) uint32_t*)(void*)(ldst), 16, 0, 0)

constexpr int B_ = 4, S_ = 2048, D_ = 1024, H_ = 16, DH_ = 64;

// ---------- prep: W[H][D][64] -> Wt[H*64][D] bf16 (B^T layout) ----------
__global__ __launch_bounds__(256) void prep_w(const float* __restrict__ W,
                                              bf16_t* __restrict__ Wt) {
  __shared__ float tile[64][65];
  int h = blockIdx.y, k0 = blockIdx.x * 64, tid = threadIdx.x;
  int r = tid >> 2, cb = (tid & 3) * 16;
  const float* src = W + h * (D_ * DH_) + (k0 + r) * DH_ + cb;
  float4 f0 = ((const float4*)src)[0];
  float4 f1 = ((const float4*)src)[1];
  float4 f2 = ((const float4*)src)[2];
  float4 f3 = ((const float4*)src)[3];
  tile[r][cb + 0] = f0.x;  tile[r][cb + 1] = f0.y;  tile[r][cb + 2] = f0.z;  tile[r][cb + 3] = f0.w;
  tile[r][cb + 4] = f1.x;  tile[r][cb + 5] = f1.y;  tile[r][cb + 6] = f1.z;  tile[r][cb + 7] = f1.w;
  tile[r][cb + 8] = f2.x;  tile[r][cb + 9] = f2.y;  tile[r][cb + 10] = f2.z; tile[r][cb + 11] = f2.w;
  tile[r][cb + 12] = f3.x; tile[r][cb + 13] = f3.y; tile[r][cb + 14] = f3.z; tile[r][cb + 15] = f3.w;
  __syncthreads();
  int j = tid >> 2, kb = (tid & 3) * 16;
  bf16_t tmp[16] __attribute__((aligned(16)));
#pragma unroll
  for (int c = 0; c < 16; ++c) tmp[c] = (bf16_t)tile[kb + c][j];
  bf16_t* dst = Wt + (h * 64 + j) * D_ + k0 + kb;
  *(uint4*)dst = ((uint4*)tmp)[0];
  *(uint4*)(dst + 8) = ((uint4*)tmp)[1];
}

__global__ __launch_bounds__(256) void prep_wo(const float* __restrict__ W,
                                               bf16_t* __restrict__ Wt) {
  int i = (blockIdx.x * 256 + threadIdx.x) * 4;
  float4 f = *(const float4*)&W[i];
  bf16_t t[4] __attribute__((aligned(8)));
  t[0] = (bf16_t)f.x; t[1] = (bf16_t)f.y; t[2] = (bf16_t)f.z; t[3] = (bf16_t)f.w;
  *(uint2*)&Wt[i] = *(uint2*)t;
}

// ---------- QKV projection GEMM: [8192,1024] x Wt^T -> bf16 ----------
__global__ __launch_bounds__(256) void gemm_qkv(
    const float* __restrict__ Aq, const float* __restrict__ Ak, const float* __restrict__ Av,
    const bf16_t* __restrict__ Wt_all,
    bf16_t* __restrict__ Qp, bf16_t* __restrict__ Kp, bf16_t* __restrict__ Vt) {
  __shared__ __attribute__((aligned(16))) bf16_t Al[128][40];
  __shared__ __attribute__((aligned(16))) bf16_t Bl[128][40];
  int gz = blockIdx.z;
  const float* A = gz == 0 ? Aq : (gz == 1 ? Ak : Av);
  const bf16_t* W = Wt_all + gz * (D_ * D_);
  int m0 = blockIdx.x * 128, n0 = blockIdx.y * 128;
  int tid = threadIdx.x, lane = tid & 63, w = tid >> 6;
  int wm = (w & 1) * 64, wn = (w >> 1) * 64;
  int l15 = lane & 15, quad = lane >> 4;
  int srow = tid >> 1, skc = (tid & 1) * 16;

  f32x4 acc[4][4] = {};

  for (int kk = 0; kk < D_; kk += 32) {
    const float* ap = A + (m0 + srow) * D_ + kk + skc;
    float4 f0 = ((const float4*)ap)[0];
    float4 f1 = ((const float4*)ap)[1];
    float4 f2 = ((const float4*)ap)[2];
    float4 f3 = ((const float4*)ap)[3];
    bf16_t t[16] __attribute__((aligned(16)));
    t[0] = (bf16_t)f0.x;  t[1] = (bf16_t)f0.y;  t[2] = (bf16_t)f0.z;  t[3] = (bf16_t)f0.w;
    t[4] = (bf16_t)f1.x;  t[5] = (bf16_t)f1.y;  t[6] = (bf16_t)f1.z;  t[7] = (bf16_t)f1.w;
    t[8] = (bf16_t)f2.x;  t[9] = (bf16_t)f2.y;  t[10] = (bf16_t)f2.z; t[11] = (bf16_t)f2.w;
    t[12] = (bf16_t)f3.x; t[13] = (bf16_t)f3.y; t[14] = (bf16_t)f3.z; t[15] = (bf16_t)f3.w;
    *(uint4*)&Al[srow][skc] = ((uint4*)t)[0];
    *(uint4*)&Al[srow][skc + 8] = ((uint4*)t)[1];
    const uint4* bp = (const uint4*)(W + (n0 + srow) * D_ + kk + skc);
    *(uint4*)&Bl[srow][skc] = bp[0];
    *(uint4*)&Bl[srow][skc + 8] = bp[1];
    __syncthreads();
    bf16x8 af[4], bfr[4];
#pragma unroll
    for (int i = 0; i < 4; ++i) {
      af[i] = *(const bf16x8*)&Al[wm + i * 16 + l15][quad * 8];
      bfr[i] = *(const bf16x8*)&Bl[wn + i * 16 + l15][quad * 8];
    }
#pragma unroll
    for (int i = 0; i < 4; ++i)
#pragma unroll
      for (int j = 0; j < 4; ++j) acc[i][j] = MFMA16(af[i], bfr[j], acc[i][j]);
    __syncthreads();
  }

  if (gz < 2) {
    bf16_t* Out = gz == 0 ? Qp : Kp;
#pragma unroll
    for (int i = 0; i < 4; ++i)
#pragma unroll
      for (int j = 0; j < 4; ++j)
#pragma unroll
        for (int r = 0; r < 4; ++r) {
          int m = m0 + wm + i * 16 + quad * 4 + r;
          int n = n0 + wn + j * 16 + l15;
          Out[m * D_ + n] = (bf16_t)acc[i][j][r];
        }
  } else {
#pragma unroll
    for (int i = 0; i < 4; ++i)
#pragma unroll
      for (int j = 0; j < 4; ++j) {
        int m = m0 + wm + i * 16 + quad * 4;
        int b = m >> 11, sl = m & (S_ - 1);
        int n = n0 + wn + j * 16 + l15;
        int h = n >> 6, d = n & 63;
        bf16_t t4[4] __attribute__((aligned(8)));
        t4[0] = (bf16_t)acc[i][j][0]; t4[1] = (bf16_t)acc[i][j][1];
        t4[2] = (bf16_t)acc[i][j][2]; t4[3] = (bf16_t)acc[i][j][3];
        *(uint2*)&Vt[((b * H_ + h) * DH_ + d) * S_ + sl] = *(uint2*)t4;
      }
  }
}

// ---------- flash attention, causal, S^T formulation ----------
// Block: 64 q rows (4 waves x 16), processes q-tiles {bidx, 31-bidx} -> 33 iters/block.
// LDS: K dbuf 16KB + V dbuf 16KB + Pt 8KB = 40KB -> 4 blocks/CU.
__global__ __launch_bounds__(256, 4) void attn(
    const bf16_t* __restrict__ Qp, const bf16_t* __restrict__ Kp,
    const bf16_t* __restrict__ Vt, bf16_t* __restrict__ Ob) {
  __shared__ __attribute__((aligned(16))) bf16_t Kl[2][4096];  // [t][d] 64x64, col8^=(t&7)
  __shared__ __attribute__((aligned(16))) bf16_t Vl[2][4096];  // [v][t] 64x64, col8^=(v&7)
  __shared__ __attribute__((aligned(16))) bf16_t Pt[4][1024];  // per-wave [s][t] 16x64, col8^=(s&7)

  int bidx = blockIdx.x;                       // 0..15
  int bh = blockIdx.y, b = bh >> 4, h = bh & 15;
  int tid = threadIdx.x, lane = tid & 63, w = tid >> 6;
  int l15 = lane & 15, quad = lane >> 4;
  int sw = l15 & 7;
  const float csc = 0.125f * 1.44269504f;      // 1/sqrt(64) * log2(e)

  bf16_t* Ptw = Pt[w];
  int rr = lane >> 3, cc = lane & 7;
  int colsw = ((cc ^ rr) * 8);                 // swizzled source col (elems)

#pragma unroll 1
  for (int ph = 0; ph < 2; ++ph) {
    int qt = ph ? 31 - bidx : bidx;

    // Q as B-operand: B[k=d][n=s], n=l15, k=quad*8+j (+32)
    int sg_base = qt * 64 + w * 16;
    const bf16_t* qptr = Qp + (size_t)(b * S_ + sg_base + l15) * D_ + h * DH_ + quad * 8;
    bf16x8 qa0 = *(const bf16x8*)qptr;
    bf16x8 qa1 = *(const bf16x8*)(qptr + 32);

    f32x4 o[4] = {};
    float m = -3.0e38f, l = 0.f;

    __syncthreads();  // protect K/V buffers from previous phase readers

    // prologue: issue loads for jt=0 into buf 0
    {
      const bf16_t* kb = Kp + (size_t)(b * S_) * D_ + h * DH_ + colsw;
      const bf16_t* vb = Vt + (size_t)(bh * DH_) * S_ + colsw;
#pragma unroll
      for (int ro = 0; ro < 2; ++ro) {
        int tl = (ro * 4 + w) * 8 + rr;
        GLOAD_LDS16(kb + (size_t)tl * D_, &Kl[0][(ro * 4 + w) * 512]);
        GLOAD_LDS16(vb + (size_t)tl * S_, &Vl[0][(ro * 4 + w) * 512]);
      }
    }

    for (int jt = 0; jt <= qt; ++jt) {
      __syncthreads();  // drains vmcnt -> buf[jt&1] ready; prior compute done

      if (jt < qt) {
        int nb = (jt + 1) & 1;
        const bf16_t* kb = Kp + (size_t)(b * S_ + (jt + 1) * 64) * D_ + h * DH_ + colsw;
        const bf16_t* vb = Vt + (size_t)(bh * DH_) * S_ + (jt + 1) * 64 + colsw;
#pragma unroll
        for (int ro = 0; ro < 2; ++ro) {
          int tl = (ro * 4 + w) * 8 + rr;
          GLOAD_LDS16(kb + (size_t)tl * D_, &Kl[nb][(ro * 4 + w) * 512]);
          GLOAD_LDS16(vb + (size_t)tl * S_, &Vl[nb][(ro * 4 + w) * 512]);
        }
      }

      const bf16_t* Kb = Kl[jt & 1];
      const bf16_t* Vb = Vl[jt & 1];
      bool diag = (jt == qt);

      // S^T = K * Q^T : C row = t = n*16+quad*4+r, col = s = l15
      f32x4 sc[4];
#pragma unroll
      for (int n = 0; n < 4; ++n) {
        if (diag && n > w) {
          sc[n] = (f32x4){-3.0e38f, -3.0e38f, -3.0e38f, -3.0e38f};
          continue;
        }
        bf16x8 kb0 = *(const bf16x8*)&Kb[(n * 16 + l15) * 64 + ((quad) ^ sw) * 8];
        bf16x8 kb1 = *(const bf16x8*)&Kb[(n * 16 + l15) * 64 + ((quad + 4) ^ sw) * 8];
        f32x4 z = {};
        z = MFMA16(kb0, qa0, z);
        z = MFMA16(kb1, qa1, z);
        if (diag && n == w) {
#pragma unroll
          for (int r = 0; r < 4; ++r)
            if (quad * 4 + r > l15) z[r] = -3.0e38f;
        }
        sc[n] = z;
      }

      // online softmax: each lane owns one q-row (s = l15)
      float mx = -3.0e38f;
#pragma unroll
      for (int n = 0; n < 4; ++n)
#pragma unroll
        for (int r = 0; r < 4; ++r) mx = fmaxf(mx, sc[n][r]);
      mx = fmaxf(mx, __shfl_xor(mx, 16));
      mx = fmaxf(mx, __shfl_xor(mx, 32));
      float mnew = fmaxf(m, mx);
      float alpha = __builtin_amdgcn_exp2f((m - mnew) * csc);
      m = mnew;
      float msc = mnew * csc;

      float rs = 0.f;
      uint32_t pk[4][2];
#pragma unroll
      for (int n = 0; n < 4; ++n) {
        bf16_t pb[4] __attribute__((aligned(8)));
#pragma unroll
        for (int r = 0; r < 4; ++r) {
          float p = __builtin_amdgcn_exp2f(sc[n][r] * csc - msc);
          rs += p;
          pb[r] = (bf16_t)p;
        }
        pk[n][0] = ((uint32_t*)pb)[0];
        pk[n][1] = ((uint32_t*)pb)[1];
      }
      rs += __shfl_xor(rs, 16);
      rs += __shfl_xor(rs, 32);
      l = l * alpha + rs;

      // P^T -> LDS (b64 packed), per-wave private
#pragma unroll
      for (int n = 0; n < 4; ++n) {
        int off = l15 * 64 + ((n * 2 + (quad >> 1)) ^ sw) * 8 + (quad & 1) * 4;
        *(uint2*)&Ptw[off] = make_uint2(pk[n][0], pk[n][1]);
      }
#pragma unroll
      for (int n = 0; n < 4; ++n) o[n] *= alpha;

      asm volatile("s_waitcnt lgkmcnt(0)" ::: "memory");  // wave-private P round-trip

      bf16x8 pb0 = *(const bf16x8*)&Ptw[l15 * 64 + ((quad) ^ sw) * 8];
      bf16x8 pb1 = *(const bf16x8*)&Ptw[l15 * 64 + ((quad + 4) ^ sw) * 8];

      // O^T += V^T * P^T : A = V^T frag (m=v, k=t), B = P^T
#pragma unroll
      for (int n = 0; n < 4; ++n) {
        bf16x8 va0 = *(const bf16x8*)&Vb[(n * 16 + l15) * 64 + ((quad) ^ sw) * 8];
        bf16x8 va1 = *(const bf16x8*)&Vb[(n * 16 + l15) * 64 + ((quad + 4) ^ sw) * 8];
        o[n] = MFMA16(va0, pb0, o[n]);
        o[n] = MFMA16(va1, pb1, o[n]);
      }
    }

    // epilogue: transpose O^T via per-wave LDS, coalesced store
    float inv = 1.0f / l;
    asm volatile("s_waitcnt lgkmcnt(0)" ::: "memory");
#pragma unroll
    for (int n = 0; n < 4; ++n) {
      bf16_t t4[4] __attribute__((aligned(8)));
#pragma unroll
      for (int r = 0; r < 4; ++r) t4[r] = (bf16_t)(o[n][r] * inv);
      int off = l15 * 64 + ((n * 2 + (quad >> 1)) ^ sw) * 8 + (quad & 1) * 4;
      *(uint2*)&Ptw[off] = *(uint2*)t4;
    }
    asm volatile("s_waitcnt lgkmcnt(0)" ::: "memory");
    {
      int sg = qt * 64 + w * 16 + l15;
      bf16x8 r0 = *(const bf16x8*)&Ptw[l15 * 64 + ((quad * 2) ^ sw) * 8];
      bf16x8 r1 = *(const bf16x8*)&Ptw[l15 * 64 + ((quad * 2 + 1) ^ sw) * 8];
      bf16_t* op = Ob + (size_t)(b * S_ + sg) * D_ + h * DH_ + quad * 16;
      *(bf16x8*)op = r0;
      *(bf16x8*)(op + 8) = r1;
    }
  }
}

// ---------- output projection: Ab[8192,1024]bf16 @ Wo^T + bo -> fp32 ----------
__global__ __launch_bounds__(256) void gemm_out(
    const bf16_t* __restrict__ Ab, const bf16_t* __restrict__ Wot,
    const float* __restrict__ bo, float* __restrict__ Out) {
  __shared__ __attribute__((aligned(16))) bf16_t Al[128][40];
  __shared__ __attribute__((aligned(16))) bf16_t Bl[128][40];
  int m0 = blockIdx.x * 128, n0 = blockIdx.y * 128;
  int tid = threadIdx.x, lane = tid & 63, w = tid >> 6;
  int wm = (w & 1) * 64, wn = (w >> 1) * 64;
  int l15 = lane & 15, quad = lane >> 4;
  int srow = tid >> 1, skc = (tid & 1) * 16;

  f32x4 acc[4][4] = {};

  for (int kk = 0; kk < D_; kk += 32) {
    const uint4* ap = (const uint4*)(Ab + (m0 + srow) * D_ + kk + skc);
    *(uint4*)&Al[srow][skc] = ap[0];
    *(uint4*)&Al[srow][skc + 8] = ap[1];
    const uint4* bp = (const uint4*)(Wot + (n0 + srow) * D_ + kk + skc);
    *(uint4*)&Bl[srow][skc] = bp[0];
    *(uint4*)&Bl[srow][skc + 8] = bp[1];
    __syncthreads();
    bf16x8 af[4], bfr[4];
#pragma unroll
    for (int i = 0; i < 4; ++i) {
      af[i] = *(const bf16x8*)&Al[wm + i * 16 + l15][quad * 8];
      bfr[i] = *(const bf16x8*)&Bl[wn + i * 16 + l15][quad * 8];
    }
#pragma unroll
    for (int i = 0; i < 4; ++i)
#pragma unroll
      for (int j = 0; j < 4; ++j) acc[i][j] = MFMA16(af[i], bfr[j], acc[i][j]);
    __syncthreads();
  }

#pragma unroll
  for (int j = 0; j < 4; ++j) {
    int n = n0 + wn + j * 16 + l15;
    float bias = bo[n];
#pragma unroll
    for (int i = 0; i < 4; ++i)
#pragma unroll
      for (int r = 0; r < 4; ++r) {
        int m = m0 + wm + i * 16 + quad * 4 + r;
        Out[m * D_ + n] = acc[i][j][r] + bias;
      }
  }
}

extern "C" void kernel_launch(void* const* d_in, const int* in_sizes, int n_in,
                              void* d_out, int out_size, void* d_ws, size_t ws_size,
                              hipStream_t stream) {
  const float* q = (const float*)d_in[0];
  const float* k = (const float*)d_in[1];
  const float* v = (const float*)d_in[2];
  const float* Wq = (const float*)d_in[3];
  const float* Wk = (const float*)d_in[4];
  const float* Wv = (const float*)d_in[5];
  const float* Wo = (const float*)d_in[6];
  const float* bo = (const float*)d_in[7];
  float* out = (float*)d_out;

  bf16_t* wsb = (bf16_t*)d_ws;
  const size_t MD = (size_t)8192 * 1024;
  bf16_t* Wqt = wsb;
  bf16_t* Wot = wsb + 3 * (size_t)(D_ * D_);
  bf16_t* Qp  = wsb + 4 * (size_t)(D_ * D_);
  bf16_t* Kp  = Qp + MD;
  bf16_t* Vt  = Kp + MD;
  bf16_t* Ab  = Vt + MD;

  prep_w<<<dim3(16, 16), 256, 0, stream>>>(Wq, Wqt);
  prep_w<<<dim3(16, 16), 256, 0, stream>>>(Wk, Wqt + (size_t)(D_ * D_));
  prep_w<<<dim3(16, 16), 256, 0, stream>>>(Wv, Wqt + 2 * (size_t)(D_ * D_));
  prep_wo<<<1024, 256, 0, stream>>>(Wo, Wot);
  gemm_qkv<<<dim3(64, 8, 3), 256, 0, stream>>>(q, k, v, Wqt, Qp, Kp, Vt);
  attn<<<dim3(16, 64), 256, 0, stream>>>(Qp, Kp, Vt, Ab);
  gemm_out<<<dim3(64, 8), 256, 0, stream>>>(Ab, Wot, bo, out);
}

// Round 3
// 352.109 us; speedup vs baseline: 1.4274x; 1.0622x over previous
//
#include <hip/hip_runtime.h>

typedef __bf16 bf16_t;
typedef __bf16 bf16x8 __attribute__((ext_vector_type(8)));
typedef float f32x4 __attribute__((ext_vector_type(4)));

#define MFMA16(a, b, c) __builtin_amdgcn_mfma_f32_16x16x32_bf16((a), (b), (c), 0, 0, 0)

// async global->LDS, 16B per lane; LDS dest = wave-uniform base + lane*16
#define GLOAD_LDS16(gsrc, ldst)                                                      \
  __builtin_amdgcn_global_load_lds(                                                  \
      (const __attribute__((address_space(1))) uint32_t*)(const void*)(gsrc),        \
      (__attribute__((address_space(3))) uint32_t*)(void*)(ldst), 16, 0, 0)

constexpr int B_ = 4, S_ = 2048, D_ = 1024, H_ = 16, DH_ = 64;

// ---------- prep: W[H][D][64] -> Wt[H*64][D] bf16 (B^T layout) ----------
__global__ __launch_bounds__(256) void prep_w(const float* __restrict__ W,
                                              bf16_t* __restrict__ Wt) {
  __shared__ float tile[64][65];
  int h = blockIdx.y, k0 = blockIdx.x * 64, tid = threadIdx.x;
  int r = tid >> 2, cb = (tid & 3) * 16;
  const float* src = W + h * (D_ * DH_) + (k0 + r) * DH_ + cb;
  float4 f0 = ((const float4*)src)[0];
  float4 f1 = ((const float4*)src)[1];
  float4 f2 = ((const float4*)src)[2];
  float4 f3 = ((const float4*)src)[3];
  tile[r][cb + 0] = f0.x;  tile[r][cb + 1] = f0.y;  tile[r][cb + 2] = f0.z;  tile[r][cb + 3] = f0.w;
  tile[r][cb + 4] = f1.x;  tile[r][cb + 5] = f1.y;  tile[r][cb + 6] = f1.z;  tile[r][cb + 7] = f1.w;
  tile[r][cb + 8] = f2.x;  tile[r][cb + 9] = f2.y;  tile[r][cb + 10] = f2.z; tile[r][cb + 11] = f2.w;
  tile[r][cb + 12] = f3.x; tile[r][cb + 13] = f3.y; tile[r][cb + 14] = f3.z; tile[r][cb + 15] = f3.w;
  __syncthreads();
  int j = tid >> 2, kb = (tid & 3) * 16;
  bf16_t tmp[16] __attribute__((aligned(16)));
#pragma unroll
  for (int c = 0; c < 16; ++c) tmp[c] = (bf16_t)tile[kb + c][j];
  bf16_t* dst = Wt + (h * 64 + j) * D_ + k0 + kb;
  *(uint4*)dst = ((uint4*)tmp)[0];
  *(uint4*)(dst + 8) = ((uint4*)tmp)[1];
}

__global__ __launch_bounds__(256) void prep_wo(const float* __restrict__ W,
                                               bf16_t* __restrict__ Wt) {
  int i = (blockIdx.x * 256 + threadIdx.x) * 4;
  float4 f = *(const float4*)&W[i];
  bf16_t t[4] __attribute__((aligned(8)));
  t[0] = (bf16_t)f.x; t[1] = (bf16_t)f.y; t[2] = (bf16_t)f.z; t[3] = (bf16_t)f.w;
  *(uint2*)&Wt[i] = *(uint2*)t;
}

// ---------- QKV projection GEMM, m97-style ----------
// A fp32 staged via global_load_lds (source-XOR-swizzled cols), B bf16 linear.
// Tile 128x128, BK=32, 4 waves each owning a 64x64 quadrant (4x4 16x16x32 MFMA).
__global__ __launch_bounds__(256) void gemm_qkv(
    const float* __restrict__ Aq, const float* __restrict__ Ak, const float* __restrict__ Av,
    const bf16_t* __restrict__ Wt_all,
    bf16_t* __restrict__ Qp, bf16_t* __restrict__ Kp, bf16_t* __restrict__ Vt) {
  __shared__ __attribute__((aligned(16))) float  Afl[128 * 32];   // 16 KB, [row][chunk^row&7]
  __shared__ __attribute__((aligned(16))) bf16_t Bl[128 * 32];    // 8 KB,  [n][k] linear
  int gz = blockIdx.z;
  const float* A = gz == 0 ? Aq : (gz == 1 ? Ak : Av);
  const bf16_t* W = Wt_all + gz * (D_ * D_);
  int m0 = blockIdx.x * 128, n0 = blockIdx.y * 128;
  int tid = threadIdx.x, lane = tid & 63, w = tid >> 6;
  int wm = (w & 1) * 64, wn = (w >> 1) * 64;
  int l15 = lane & 15, quad = lane >> 4;
  int sw = l15 & 7;

  // staging lane maps
  int ar = lane >> 3;                         // row within 8-row chunk
  int acol = ((lane & 7) ^ ar) * 4;           // swizzled fp32 col
  int br = lane >> 2;                         // row within 16-row chunk
  int bcol = (lane & 3) * 8;                  // bf16 col

  f32x4 acc[4][4] = {};

  for (int kk = 0; kk < D_; kk += 32) {
    const float* abase = A + (size_t)m0 * D_ + kk + acol;
#pragma unroll
    for (int it = 0; it < 4; ++it) {
      int chunk = it * 4 + w;                 // 0..15, 8 rows each
      GLOAD_LDS16(abase + (size_t)(chunk * 8 + ar) * D_, &Afl[chunk * 256]);
    }
    const bf16_t* bbase = W + (size_t)n0 * D_ + kk + bcol;
#pragma unroll
    for (int ib = 0; ib < 2; ++ib) {
      int chunk = ib * 4 + w;                 // 0..7, 16 rows each
      GLOAD_LDS16(bbase + (size_t)(chunk * 16 + br) * D_, &Bl[chunk * 512]);
    }
    __syncthreads();

    bf16x8 af[4], bf[4];
#pragma unroll
    for (int i = 0; i < 4; ++i) {
      int ra = wm + i * 16 + l15;
      float4 f0 = *(const float4*)&Afl[ra * 32 + (((quad * 2) ^ sw) << 2)];
      float4 f1 = *(const float4*)&Afl[ra * 32 + (((quad * 2 + 1) ^ sw) << 2)];
      bf16x8 a;
      a[0] = (bf16_t)f0.x; a[1] = (bf16_t)f0.y; a[2] = (bf16_t)f0.z; a[3] = (bf16_t)f0.w;
      a[4] = (bf16_t)f1.x; a[5] = (bf16_t)f1.y; a[6] = (bf16_t)f1.z; a[7] = (bf16_t)f1.w;
      af[i] = a;
      bf[i] = *(const bf16x8*)&Bl[(wn + i * 16 + l15) * 32 + quad * 8];
    }
#pragma unroll
    for (int i = 0; i < 4; ++i)
#pragma unroll
      for (int j = 0; j < 4; ++j) acc[i][j] = MFMA16(af[i], bf[j], acc[i][j]);
    __syncthreads();
  }

  if (gz < 2) {
    bf16_t* Out = gz == 0 ? Qp : Kp;
#pragma unroll
    for (int i = 0; i < 4; ++i)
#pragma unroll
      for (int j = 0; j < 4; ++j)
#pragma unroll
        for (int r = 0; r < 4; ++r) {
          int m = m0 + wm + i * 16 + quad * 4 + r;
          int n = n0 + wn + j * 16 + l15;
          Out[(size_t)m * D_ + n] = (bf16_t)acc[i][j][r];
        }
  } else {
#pragma unroll
    for (int i = 0; i < 4; ++i)
#pragma unroll
      for (int j = 0; j < 4; ++j) {
        int m = m0 + wm + i * 16 + quad * 4;
        int b = m >> 11, sl = m & (S_ - 1);
        int n = n0 + wn + j * 16 + l15;
        int h = n >> 6, d = n & 63;
        bf16_t t4[4] __attribute__((aligned(8)));
        t4[0] = (bf16_t)acc[i][j][0]; t4[1] = (bf16_t)acc[i][j][1];
        t4[2] = (bf16_t)acc[i][j][2]; t4[3] = (bf16_t)acc[i][j][3];
        *(uint2*)&Vt[((size_t)(b * H_ + h) * DH_ + d) * S_ + sl] = *(uint2*)t4;
      }
  }
}

// ---------- flash attention, causal, S^T formulation (unchanged) ----------
__global__ __launch_bounds__(256, 4) void attn(
    const bf16_t* __restrict__ Qp, const bf16_t* __restrict__ Kp,
    const bf16_t* __restrict__ Vt, bf16_t* __restrict__ Ob) {
  __shared__ __attribute__((aligned(16))) bf16_t Kl[2][4096];
  __shared__ __attribute__((aligned(16))) bf16_t Vl[2][4096];
  __shared__ __attribute__((aligned(16))) bf16_t Pt[4][1024];

  int bidx = blockIdx.x;
  int bh = blockIdx.y, b = bh >> 4, h = bh & 15;
  int tid = threadIdx.x, lane = tid & 63, w = tid >> 6;
  int l15 = lane & 15, quad = lane >> 4;
  int sw = l15 & 7;
  const float csc = 0.125f * 1.44269504f;

  bf16_t* Ptw = Pt[w];
  int rr = lane >> 3, cc = lane & 7;
  int colsw = ((cc ^ rr) * 8);

#pragma unroll 1
  for (int ph = 0; ph < 2; ++ph) {
    int qt = ph ? 31 - bidx : bidx;

    int sg_base = qt * 64 + w * 16;
    const bf16_t* qptr = Qp + (size_t)(b * S_ + sg_base + l15) * D_ + h * DH_ + quad * 8;
    bf16x8 qa0 = *(const bf16x8*)qptr;
    bf16x8 qa1 = *(const bf16x8*)(qptr + 32);

    f32x4 o[4] = {};
    float m = -3.0e38f, l = 0.f;

    __syncthreads();

    {
      const bf16_t* kb = Kp + (size_t)(b * S_) * D_ + h * DH_ + colsw;
      const bf16_t* vb = Vt + (size_t)(bh * DH_) * S_ + colsw;
#pragma unroll
      for (int ro = 0; ro < 2; ++ro) {
        int tl = (ro * 4 + w) * 8 + rr;
        GLOAD_LDS16(kb + (size_t)tl * D_, &Kl[0][(ro * 4 + w) * 512]);
        GLOAD_LDS16(vb + (size_t)tl * S_, &Vl[0][(ro * 4 + w) * 512]);
      }
    }

    for (int jt = 0; jt <= qt; ++jt) {
      __syncthreads();

      if (jt < qt) {
        int nb = (jt + 1) & 1;
        const bf16_t* kb = Kp + (size_t)(b * S_ + (jt + 1) * 64) * D_ + h * DH_ + colsw;
        const bf16_t* vb = Vt + (size_t)(bh * DH_) * S_ + (jt + 1) * 64 + colsw;
#pragma unroll
        for (int ro = 0; ro < 2; ++ro) {
          int tl = (ro * 4 + w) * 8 + rr;
          GLOAD_LDS16(kb + (size_t)tl * D_, &Kl[nb][(ro * 4 + w) * 512]);
          GLOAD_LDS16(vb + (size_t)tl * S_, &Vl[nb][(ro * 4 + w) * 512]);
        }
      }

      const bf16_t* Kb = Kl[jt & 1];
      const bf16_t* Vb = Vl[jt & 1];
      bool diag = (jt == qt);

      f32x4 sc[4];
#pragma unroll
      for (int n = 0; n < 4; ++n) {
        if (diag && n > w) {
          sc[n] = (f32x4){-3.0e38f, -3.0e38f, -3.0e38f, -3.0e38f};
          continue;
        }
        bf16x8 kb0 = *(const bf16x8*)&Kb[(n * 16 + l15) * 64 + ((quad) ^ sw) * 8];
        bf16x8 kb1 = *(const bf16x8*)&Kb[(n * 16 + l15) * 64 + ((quad + 4) ^ sw) * 8];
        f32x4 z = {};
        z = MFMA16(kb0, qa0, z);
        z = MFMA16(kb1, qa1, z);
        if (diag && n == w) {
#pragma unroll
          for (int r = 0; r < 4; ++r)
            if (quad * 4 + r > l15) z[r] = -3.0e38f;
        }
        sc[n] = z;
      }

      float mx = -3.0e38f;
#pragma unroll
      for (int n = 0; n < 4; ++n)
#pragma unroll
        for (int r = 0; r < 4; ++r) mx = fmaxf(mx, sc[n][r]);
      mx = fmaxf(mx, __shfl_xor(mx, 16));
      mx = fmaxf(mx, __shfl_xor(mx, 32));
      float mnew = fmaxf(m, mx);
      float alpha = __builtin_amdgcn_exp2f((m - mnew) * csc);
      m = mnew;
      float msc = mnew * csc;

      float rs = 0.f;
      uint32_t pk[4][2];
#pragma unroll
      for (int n = 0; n < 4; ++n) {
        bf16_t pb[4] __attribute__((aligned(8)));
#pragma unroll
        for (int r = 0; r < 4; ++r) {
          float p = __builtin_amdgcn_exp2f(sc[n][r] * csc - msc);
          rs += p;
          pb[r] = (bf16_t)p;
        }
        pk[n][0] = ((uint32_t*)pb)[0];
        pk[n][1] = ((uint32_t*)pb)[1];
      }
      rs += __shfl_xor(rs, 16);
      rs += __shfl_xor(rs, 32);
      l = l * alpha + rs;

#pragma unroll
      for (int n = 0; n < 4; ++n) {
        int off = l15 * 64 + ((n * 2 + (quad >> 1)) ^ sw) * 8 + (quad & 1) * 4;
        *(uint2*)&Ptw[off] = make_uint2(pk[n][0], pk[n][1]);
      }
#pragma unroll
      for (int n = 0; n < 4; ++n) o[n] *= alpha;

      asm volatile("s_waitcnt lgkmcnt(0)" ::: "memory");

      bf16x8 pb0 = *(const bf16x8*)&Ptw[l15 * 64 + ((quad) ^ sw) * 8];
      bf16x8 pb1 = *(const bf16x8*)&Ptw[l15 * 64 + ((quad + 4) ^ sw) * 8];

#pragma unroll
      for (int n = 0; n < 4; ++n) {
        bf16x8 va0 = *(const bf16x8*)&Vb[(n * 16 + l15) * 64 + ((quad) ^ sw) * 8];
        bf16x8 va1 = *(const bf16x8*)&Vb[(n * 16 + l15) * 64 + ((quad + 4) ^ sw) * 8];
        o[n] = MFMA16(va0, pb0, o[n]);
        o[n] = MFMA16(va1, pb1, o[n]);
      }
    }

    float inv = 1.0f / l;
    asm volatile("s_waitcnt lgkmcnt(0)" ::: "memory");
#pragma unroll
    for (int n = 0; n < 4; ++n) {
      bf16_t t4[4] __attribute__((aligned(8)));
#pragma unroll
      for (int r = 0; r < 4; ++r) t4[r] = (bf16_t)(o[n][r] * inv);
      int off = l15 * 64 + ((n * 2 + (quad >> 1)) ^ sw) * 8 + (quad & 1) * 4;
      *(uint2*)&Ptw[off] = *(uint2*)t4;
    }
    asm volatile("s_waitcnt lgkmcnt(0)" ::: "memory");
    {
      int sg = qt * 64 + w * 16 + l15;
      bf16x8 r0 = *(const bf16x8*)&Ptw[l15 * 64 + ((quad * 2) ^ sw) * 8];
      bf16x8 r1 = *(const bf16x8*)&Ptw[l15 * 64 + ((quad * 2 + 1) ^ sw) * 8];
      bf16_t* op = Ob + (size_t)(b * S_ + sg) * D_ + h * DH_ + quad * 16;
      *(bf16x8*)op = r0;
      *(bf16x8*)(op + 8) = r1;
    }
  }
}

// ---------- output projection, m97-style: Ab bf16 @ Wo^T + bo -> fp32 ----------
__global__ __launch_bounds__(256) void gemm_out(
    const bf16_t* __restrict__ Ab, const bf16_t* __restrict__ Wot,
    const float* __restrict__ bo, float* __restrict__ Out) {
  __shared__ __attribute__((aligned(16))) bf16_t Al[128 * 32];
  __shared__ __attribute__((aligned(16))) bf16_t Bl[128 * 32];
  int m0 = blockIdx.x * 128, n0 = blockIdx.y * 128;
  int tid = threadIdx.x, lane = tid & 63, w = tid >> 6;
  int wm = (w & 1) * 64, wn = (w >> 1) * 64;
  int l15 = lane & 15, quad = lane >> 4;
  int br = lane >> 2, bcol = (lane & 3) * 8;

  f32x4 acc[4][4] = {};

  for (int kk = 0; kk < D_; kk += 32) {
    const bf16_t* abase = Ab + (size_t)m0 * D_ + kk + bcol;
    const bf16_t* bbase = Wot + (size_t)n0 * D_ + kk + bcol;
#pragma unroll
    for (int ib = 0; ib < 2; ++ib) {
      int chunk = ib * 4 + w;
      GLOAD_LDS16(abase + (size_t)(chunk * 16 + br) * D_, &Al[chunk * 512]);
      GLOAD_LDS16(bbase + (size_t)(chunk * 16 + br) * D_, &Bl[chunk * 512]);
    }
    __syncthreads();
    bf16x8 af[4], bf[4];
#pragma unroll
    for (int i = 0; i < 4; ++i) {
      af[i] = *(const bf16x8*)&Al[(wm + i * 16 + l15) * 32 + quad * 8];
      bf[i] = *(const bf16x8*)&Bl[(wn + i * 16 + l15) * 32 + quad * 8];
    }
#pragma unroll
    for (int i = 0; i < 4; ++i)
#pragma unroll
      for (int j = 0; j < 4; ++j) acc[i][j] = MFMA16(af[i], bf[j], acc[i][j]);
    __syncthreads();
  }

#pragma unroll
  for (int j = 0; j < 4; ++j) {
    int n = n0 + wn + j * 16 + l15;
    float bias = bo[n];
#pragma unroll
    for (int i = 0; i < 4; ++i)
#pragma unroll
      for (int r = 0; r < 4; ++r) {
        int m = m0 + wm + i * 16 + quad * 4 + r;
        Out[(size_t)m * D_ + n] = acc[i][j][r] + bias;
      }
  }
}

extern "C" void kernel_launch(void* const* d_in, const int* in_sizes, int n_in,
                              void* d_out, int out_size, void* d_ws, size_t ws_size,
                              hipStream_t stream) {
  const float* q = (const float*)d_in[0];
  const float* k = (const float*)d_in[1];
  const float* v = (const float*)d_in[2];
  const float* Wq = (const float*)d_in[3];
  const float* Wk = (const float*)d_in[4];
  const float* Wv = (const float*)d_in[5];
  const float* Wo = (const float*)d_in[6];
  const float* bo = (const float*)d_in[7];
  float* out = (float*)d_out;

  bf16_t* wsb = (bf16_t*)d_ws;
  const size_t MD = (size_t)8192 * 1024;
  bf16_t* Wqt = wsb;
  bf16_t* Wot = wsb + 3 * (size_t)(D_ * D_);
  bf16_t* Qp  = wsb + 4 * (size_t)(D_ * D_);
  bf16_t* Kp  = Qp + MD;
  bf16_t* Vt  = Kp + MD;
  bf16_t* Ab  = Vt + MD;

  prep_w<<<dim3(16, 16), 256, 0, stream>>>(Wq, Wqt);
  prep_w<<<dim3(16, 16), 256, 0, stream>>>(Wk, Wqt + (size_t)(D_ * D_));
  prep_w<<<dim3(16, 16), 256, 0, stream>>>(Wv, Wqt + 2 * (size_t)(D_ * D_));
  prep_wo<<<1024, 256, 0, stream>>>(Wo, Wot);
  gemm_qkv<<<dim3(64, 8, 3), 256, 0, stream>>>(q, k, v, Wqt, Qp, Kp, Vt);
  attn<<<dim3(16, 64), 256, 0, stream>>>(Qp, Kp, Vt, Ab);
  gemm_out<<<dim3(64, 8), 256, 0, stream>>>(Ab, Wot, bo, out);
}